// Round 15
// baseline (56.460 us; speedup 1.0000x reference)
//
#include <hip/hip_runtime.h>

// Window attention, b=8 s=4094 nh=8 h=64, radius 63, f32 I/O.
// Round 15: single-barrier at r13 geometry (controlled test of structure
// vs occupancy). 512-thr blocks / 128 q; K [256][64] bf16 (32 KiB) and
// V^T [64][272] bf16 (34 KiB) in SEPARATE buffers; Q+K+V loads issue as
// one pipelined burst; ONE __syncthreads(); then QK -> no-max exp2
// softmax -> shuffle P -> PV -> store with no further barriers.
//   r9  = 16 waves/CU, 3 barriers, 2 HBM round-trips: 56.6 us
//   r13 = 32 waves/CU, 3 barriers, 2 round-trips:     53.5 us
//   this = 16 waves/CU, 1 barrier, 1 round-trip:      ?
// All staging/compute pieces verbatim r13 -- only ordering changed.
//
// MFMA 16x16x32 bf16 layouts (verified rounds 1-14):
//   A: lane l holds A[row=l&15][k=(l>>4)*8+j]   B: B[k=(l>>4)*8+j][col=l&15]
//   D: lane l reg r holds D[row=(l>>4)*4+r][col=l&15]

#define S_LEN 4094
#define NHEAD 8
#define HDIM  64
#define ROWSTR 512
#define KTILE 256            // staged K rows (keys)
#define VTILE 272            // staged V^T cols (keys)

typedef float f32x4 __attribute__((ext_vector_type(4)));
typedef short s16x8 __attribute__((ext_vector_type(8)));
typedef int   i32x2 __attribute__((ext_vector_type(2)));
typedef int   i32x4 __attribute__((ext_vector_type(4)));

#define QSCALE 0.1803368801f   // 0.125 * log2(e)

static __device__ __forceinline__ unsigned cvt_pk(float lo, float hi) {
    unsigned r;
    asm("v_cvt_pk_bf16_f32 %0, %1, %2" : "=v"(r) : "v"(lo), "v"(hi));
    return r;
}

// K view: [256 keys][64 h] bf16, row 128 B, swizzle ^((key&7)<<4)
static __device__ __forceinline__ int koff(int kr, int h) {
    return ((kr << 7) + (h << 1)) ^ ((kr & 7) << 4);
}
// V^T view: [64 h][272 keys] bf16, row 544 B, swizzle ^((h&7)<<4)
static __device__ __forceinline__ int voff(int h, int kc) {
    return (h * (VTILE * 2) + (kc << 1)) ^ ((h & 7) << 4);
}

static __device__ __forceinline__ f32x4 gload(const float* p, bool ok) {
    f32x4 x = {0.f, 0.f, 0.f, 0.f};
    if (ok) x = *(const f32x4*)p;
    return x;
}

static __device__ __forceinline__ s16x8 pack8(f32x4 x0, f32x4 x1) {
    i32x4 wd;
    wd[0] = (int)cvt_pk(x0[0], x0[1]); wd[1] = (int)cvt_pk(x0[2], x0[3]);
    wd[2] = (int)cvt_pk(x1[0], x1[1]); wd[3] = (int)cvt_pk(x1[2], x1[3]);
    return __builtin_bit_cast(s16x8, wd);
}

__global__ __launch_bounds__(512, 4)
void win_attn(const float* __restrict__ q, const float* __restrict__ k,
              const float* __restrict__ v, float* __restrict__ out)
{
    __shared__ __align__(16) short Klds[KTILE * 64];       // 32 KiB
    __shared__ __align__(16) short Vtld[64 * VTILE + 32];  // 34 KiB (+margin)

    const int tid  = threadIdx.x;
    const int lane = tid & 63;
    const int w    = tid >> 6;      // wave 0..7
    const int u    = lane >> 4;
    const int c16  = lane & 15;

    // ---- T1: XCD-bijective swizzle (2048 = 8 XCD x 256 contiguous) ----
    const int wg  = (int)blockIdx.x;
    const int swz = (wg & 7) * 256 + (wg >> 3);
    const int cx  = swz & 31;          // q-chunk 0..31
    const int rem = swz >> 5;
    const int hn  = rem & 7;           // head
    const int bz  = rem >> 3;          // batch

    const int q0 = cx * 128;
    const int g0 = q0 - 63;                      // key of tile index 0
    const int qw = q0 + w * 16;                  // this wave's first query
    const size_t bn = (size_t)bz * (S_LEN * ROWSTR) + (size_t)hn * HDIM;
    const float* qg = q + bn;
    const float* kg = k + bn;
    const float* vg = v + bn;

    // ---- Q loads (part of the single burst) ----
    f32x4 qld[4];
    {
        int qr = qw + c16; if (qr > S_LEN - 1) qr = S_LEN - 1;
        const float* qp = qg + (size_t)qr * ROWSTR + u * 8;
        qld[0] = *(const f32x4*)(qp);
        qld[1] = *(const f32x4*)(qp + 4);
        qld[2] = *(const f32x4*)(qp + 32);
        qld[3] = *(const f32x4*)(qp + 36);
    }

    // ---- stage K: 256 rows x 16 h-quads = 4096 units, 8/thread ----
    #pragma unroll
    for (int p = 0; p < 8; ++p) {
        int unit = p * 512 + tid;
        int kr = unit >> 4, hq = unit & 15;
        int g  = g0 + kr;
        f32x4 x = gload(kg + (size_t)g * ROWSTR + hq * 4, g >= 0 && g < S_LEN);
        i32x2 wd; wd[0] = (int)cvt_pk(x[0], x[1]); wd[1] = (int)cvt_pk(x[2], x[3]);
        *(i32x2*)((char*)Klds + koff(kr, hq * 4)) = wd;
    }

    // ---- stage V^T: 68 key-quads x 16 h-quads = 1088 units ----
    #pragma unroll
    for (int p = 0; p < 3; ++p) {
        int unit = p * 512 + tid;
        if (unit < (VTILE / 4) * 16) {
            int kq = unit >> 4, hq = unit & 15;
            int g  = g0 + kq * 4;
            f32x4 y0 = gload(vg + (size_t)(g + 0) * ROWSTR + hq * 4, g + 0 >= 0 && g + 0 < S_LEN);
            f32x4 y1 = gload(vg + (size_t)(g + 1) * ROWSTR + hq * 4, g + 1 >= 0 && g + 1 < S_LEN);
            f32x4 y2 = gload(vg + (size_t)(g + 2) * ROWSTR + hq * 4, g + 2 >= 0 && g + 2 < S_LEN);
            f32x4 y3 = gload(vg + (size_t)(g + 3) * ROWSTR + hq * 4, g + 3 >= 0 && g + 3 < S_LEN);
            #pragma unroll
            for (int ii = 0; ii < 4; ++ii) {
                int i = (ii + (hq >> 1)) & 3;        // spread h&7 across lanes
                int h = hq * 4 + i;
                i32x2 wd;
                wd[0] = (int)cvt_pk(y0[i], y1[i]);
                wd[1] = (int)cvt_pk(y2[i], y3[i]);
                *(i32x2*)((char*)Vtld + voff(h, kq * 4)) = wd;
            }
        }
    }
    __syncthreads();   // the ONLY barrier; everything staged

    // ---- QK^T (9 tiles) + no-max exp2 softmax; P packed to regs ----
    s16x8 bq[2];
    #pragma unroll
    for (int hf = 0; hf < 2; ++hf) {
        f32x4 x0 = qld[hf * 2]     * QSCALE;
        f32x4 x1 = qld[hf * 2 + 1] * QSCALE;
        bq[hf] = pack8(x0, x1);
    }

    f32x4 sc[9];
    #pragma unroll
    for (int j = 0; j < 9; ++j) {
        int krow = w * 16 + j * 16 + c16;   // <= 255
        s16x8 ka0 = *(const s16x8*)((const char*)Klds + koff(krow, u * 8));
        s16x8 ka1 = *(const s16x8*)((const char*)Klds + koff(krow, 32 + u * 8));
        f32x4 acc = {0.f, 0.f, 0.f, 0.f};
        acc = __builtin_amdgcn_mfma_f32_16x16x32_bf16(ka0, bq[0], acc, 0, 0, 0);
        acc = __builtin_amdgcn_mfma_f32_16x16x32_bf16(ka1, bq[1], acc, 0, 0, 0);
        sc[j] = acc;
    }

    // band mask (only tiles 0,7,8 can violate); exp2; P pack; 1/d deferred
    const int iq = c16;
    float d = 0.f;
    int w0[9], w1[9];
    #pragma unroll
    for (int j = 0; j < 9; ++j) {
        #pragma unroll
        for (int r = 0; r < 4; ++r) {
            float s = sc[j][r];
            if (j == 0 || j >= 7) {
                int tl = j * 16 + u * 4 + r;
                bool inb = (tl >= iq) && (tl <= iq + 126);
                s = inb ? s : -__builtin_inff();
            }
            float pv = __builtin_amdgcn_exp2f(s);   // 2^s; 2^-inf = 0
            sc[j][r] = pv;
            d += pv;
        }
    }
    #pragma unroll
    for (int j = 0; j < 9; ++j) {
        w0[j] = (int)cvt_pk(sc[j][0], sc[j][1]);
        w1[j] = (int)cvt_pk(sc[j][2], sc[j][3]);
    }
    d += __shfl_xor(d, 16, 64);
    d += __shfl_xor(d, 32, 64);
    const float rdv = 1.f / d;

    // ---- P -> A-frags (shuffles) + PV + 1/d + stores (no barriers) ----
    const int sA = ((u & 1) * 2) * 16 + c16;
    const int sB = sA + 16;
    const bool hiHalf = (u >> 1) != 0;

    s16x8 pa[5];
    #pragma unroll
    for (int kf = 0; kf < 5; ++kf) {
        const int jtA = 2 * kf;        // tile feeding dest u<2 (0..8)
        const int jtB = 2 * kf + 1;    // tile feeding dest u>=2 (9 -> zero)
        int a0, a1, b0, b1;
        int e0 = 0, e1 = 0, f0 = 0, f1 = 0;
        a0 = __shfl(w0[jtA], sA, 64); a1 = __shfl(w1[jtA], sA, 64);
        b0 = __shfl(w0[jtA], sB, 64); b1 = __shfl(w1[jtA], sB, 64);
        if (jtB <= 8) {
            e0 = __shfl(w0[jtB], sA, 64); e1 = __shfl(w1[jtB], sA, 64);
            f0 = __shfl(w0[jtB], sB, 64); f1 = __shfl(w1[jtB], sB, 64);
        }
        i32x4 wd;
        wd[0] = hiHalf ? e0 : a0;
        wd[1] = hiHalf ? e1 : a1;
        wd[2] = hiHalf ? f0 : b0;
        wd[3] = hiHalf ? f1 : b1;
        pa[kf] = __builtin_bit_cast(s16x8, wd);
    }

    // fetch 1/d for this lane's 4 output rows (queries u*4+r)
    float rq[4];
    #pragma unroll
    for (int r = 0; r < 4; ++r)
        rq[r] = __shfl(rdv, u * 4 + r, 64);

    #pragma unroll
    for (int ht = 0; ht < 4; ++ht) {
        f32x4 o = {0.f, 0.f, 0.f, 0.f};
        #pragma unroll
        for (int kf = 0; kf < 5; ++kf) {
            s16x8 bv = *(const s16x8*)((const char*)Vtld +
                         voff(ht * 16 + c16, w * 16 + kf * 32 + u * 8));   // col <= 264
            o = __builtin_amdgcn_mfma_f32_16x16x32_bf16(pa[kf], bv, o, 0, 0, 0);
        }
        #pragma unroll
        for (int r = 0; r < 4; ++r) {
            int p = qw + u * 4 + r;
            if (p < S_LEN)
                out[bn + (size_t)p * ROWSTR + ht * 16 + c16] = o[r] * rq[r];
        }
    }
}

extern "C" void kernel_launch(void* const* d_in, const int* in_sizes, int n_in,
                              void* d_out, int out_size, void* d_ws, size_t ws_size,
                              hipStream_t stream) {
    const float* q = (const float*)d_in[0];
    const float* k = (const float*)d_in[1];
    const float* v = (const float*)d_in[2];
    float* o = (float*)d_out;
    const int B = in_sizes[0] / (S_LEN * NHEAD * HDIM);
    dim3 grid(32 * NHEAD * B);   // 2048 blocks, XCD-swizzled in-kernel
    win_attn<<<grid, dim3(512), 0, stream>>>(q, k, v, o);
}

// Round 16
// 54.319 us; speedup vs baseline: 1.0394x; 1.0394x over previous
//
#include <hip/hip_runtime.h>

// Window attention, b=8 s=4094 nh=8 h=64, radius 63, f32 I/O.
// Round 16 = r13 (best, 53.5us) + DS-op compression:
//  1. K staging via ds_write_b128 (thread = row x h-oct): 8->4 writes,
//     bank start = 4*(ho^(kr&7)) -> uniform 8-deep (floor).
//  2. V^T staging via ds_write_b128 (thread = key-oct x h-quad): 12->4
//     writes; bank algebra [(8i+4kq8)&31]^[16(hq&1)+4i] -> 8 distinct
//     slot-groups -> uniform 8-deep (floor). No i-permutation needed.
//  3. Nontemporal output stores (write-once; keep L2 for K/V halo reuse).
//  4. s_setprio(1) around QK/PV MFMA clusters (T5).
// Everything else verbatim r13: 512-thr blocks / 128 q / wave=16 q,
// K [256][64] bf16 tile reused as V^T [64][272], no-max exp2 softmax,
// deferred 1/d, XCD swizzle, launch_bounds(512,4).
//
// MFMA 16x16x32 bf16 layouts (verified rounds 1-15):
//   A: lane l holds A[row=l&15][k=(l>>4)*8+j]   B: B[k=(l>>4)*8+j][col=l&15]
//   D: lane l reg r holds D[row=(l>>4)*4+r][col=l&15]

#define S_LEN 4094
#define NHEAD 8
#define HDIM  64
#define ROWSTR 512
#define KTILE 256            // staged K rows (keys)
#define VTILE 272            // staged V^T cols (keys)

typedef float f32x4 __attribute__((ext_vector_type(4)));
typedef short s16x8 __attribute__((ext_vector_type(8)));
typedef int   i32x2 __attribute__((ext_vector_type(2)));
typedef int   i32x4 __attribute__((ext_vector_type(4)));

#define QSCALE 0.1803368801f   // 0.125 * log2(e)

static __device__ __forceinline__ unsigned cvt_pk(float lo, float hi) {
    unsigned r;
    asm("v_cvt_pk_bf16_f32 %0, %1, %2" : "=v"(r) : "v"(lo), "v"(hi));
    return r;
}

// K view: [256 keys][64 h] bf16, row 128 B, swizzle ^((key&7)<<4)
static __device__ __forceinline__ int koff(int kr, int h) {
    return ((kr << 7) + (h << 1)) ^ ((kr & 7) << 4);
}
// V^T view: [64 h][272 keys] bf16, row 544 B, swizzle ^((h&7)<<4)
static __device__ __forceinline__ int voff(int h, int kc) {
    return (h * (VTILE * 2) + (kc << 1)) ^ ((h & 7) << 4);
}

static __device__ __forceinline__ f32x4 gload(const float* p, bool ok) {
    f32x4 x = {0.f, 0.f, 0.f, 0.f};
    if (ok) x = *(const f32x4*)p;
    return x;
}

static __device__ __forceinline__ s16x8 pack8(f32x4 x0, f32x4 x1) {
    i32x4 wd;
    wd[0] = (int)cvt_pk(x0[0], x0[1]); wd[1] = (int)cvt_pk(x0[2], x0[3]);
    wd[2] = (int)cvt_pk(x1[0], x1[1]); wd[3] = (int)cvt_pk(x1[2], x1[3]);
    return __builtin_bit_cast(s16x8, wd);
}

__global__ __launch_bounds__(512, 4)
void win_attn(const float* __restrict__ q, const float* __restrict__ k,
              const float* __restrict__ v, float* __restrict__ out)
{
    __shared__ __align__(16) short Tile[64 * VTILE + 64];   // 34.9 KiB, K then V^T

    const int tid  = threadIdx.x;
    const int lane = tid & 63;
    const int w    = tid >> 6;      // wave 0..7
    const int u    = lane >> 4;
    const int c16  = lane & 15;

    // ---- T1: XCD-bijective swizzle (2048 = 8 XCD x 256 contiguous) ----
    const int wg  = (int)blockIdx.x;
    const int swz = (wg & 7) * 256 + (wg >> 3);
    const int cx  = swz & 31;          // q-chunk 0..31
    const int rem = swz >> 5;
    const int hn  = rem & 7;           // head
    const int bz  = rem >> 3;          // batch

    const int q0 = cx * 128;
    const int g0 = q0 - 63;                      // key of tile index 0
    const int qw = q0 + w * 16;                  // this wave's first query
    const size_t bn = (size_t)bz * (S_LEN * ROWSTR) + (size_t)hn * HDIM;
    const float* qg = q + bn;
    const float* kg = k + bn;
    const float* vg = v + bn;

    // ---- Q loads issued first (hide under K staging) ----
    f32x4 qld[4];
    {
        int qr = qw + c16; if (qr > S_LEN - 1) qr = S_LEN - 1;
        const float* qp = qg + (size_t)qr * ROWSTR + u * 8;
        qld[0] = *(const f32x4*)(qp);
        qld[1] = *(const f32x4*)(qp + 4);
        qld[2] = *(const f32x4*)(qp + 32);
        qld[3] = *(const f32x4*)(qp + 36);
    }

    // ---- phase A: stage K. 256 rows x 8 h-octs = 2048 units, 4/thread.
    //      b128 writes, bank start 4*(ho^(kr&7)): uniform 8-deep. ----
    #pragma unroll
    for (int p = 0; p < 4; ++p) {
        int unit = p * 512 + tid;
        int kr = unit >> 3, ho = unit & 7;
        int g  = g0 + kr;
        bool ok = (g >= 0) && (g < S_LEN);
        const float* kp = kg + (size_t)g * ROWSTR + ho * 8;
        f32x4 x0 = gload(kp, ok);
        f32x4 x1 = gload(kp + 4, ok);
        i32x4 wd;
        wd[0] = (int)cvt_pk(x0[0], x0[1]); wd[1] = (int)cvt_pk(x0[2], x0[3]);
        wd[2] = (int)cvt_pk(x1[0], x1[1]); wd[3] = (int)cvt_pk(x1[2], x1[3]);
        *(i32x4*)((char*)Tile + koff(kr, ho * 8)) = wd;
    }
    __syncthreads();   // K tile ready

    // ---- phase B: QK^T (9 tiles) + no-max exp2 softmax; P packed to regs ----
    s16x8 bq[2];
    #pragma unroll
    for (int hf = 0; hf < 2; ++hf) {
        f32x4 x0 = qld[hf * 2]     * QSCALE;
        f32x4 x1 = qld[hf * 2 + 1] * QSCALE;
        bq[hf] = pack8(x0, x1);
    }

    f32x4 sc[9];
    __builtin_amdgcn_s_setprio(1);
    #pragma unroll
    for (int j = 0; j < 9; ++j) {
        int krow = w * 16 + j * 16 + c16;   // <= 255
        s16x8 ka0 = *(const s16x8*)((const char*)Tile + koff(krow, u * 8));
        s16x8 ka1 = *(const s16x8*)((const char*)Tile + koff(krow, 32 + u * 8));
        f32x4 acc = {0.f, 0.f, 0.f, 0.f};
        acc = __builtin_amdgcn_mfma_f32_16x16x32_bf16(ka0, bq[0], acc, 0, 0, 0);
        acc = __builtin_amdgcn_mfma_f32_16x16x32_bf16(ka1, bq[1], acc, 0, 0, 0);
        sc[j] = acc;
    }
    __builtin_amdgcn_s_setprio(0);

    // band mask (only tiles 0,7,8 can violate); exp2; P pack; 1/d deferred
    const int iq = c16;
    float d = 0.f;
    int w0[9], w1[9];
    #pragma unroll
    for (int j = 0; j < 9; ++j) {
        #pragma unroll
        for (int r = 0; r < 4; ++r) {
            float s = sc[j][r];
            if (j == 0 || j >= 7) {
                int tl = j * 16 + u * 4 + r;
                bool inb = (tl >= iq) && (tl <= iq + 126);
                s = inb ? s : -__builtin_inff();
            }
            float pv = __builtin_amdgcn_exp2f(s);   // 2^s; 2^-inf = 0
            sc[j][r] = pv;
            d += pv;
        }
    }
    #pragma unroll
    for (int j = 0; j < 9; ++j) {
        w0[j] = (int)cvt_pk(sc[j][0], sc[j][1]);
        w1[j] = (int)cvt_pk(sc[j][2], sc[j][3]);
    }
    d += __shfl_xor(d, 16, 64);
    d += __shfl_xor(d, 32, 64);
    const float rdv = 1.f / d;
    __syncthreads();   // all waves done reading K tile

    // ---- phase C: stage V^T. 34 key-octs x 16 h-quads = 544 units.
    //      b128 writes, 8 distinct slot-groups/instr: uniform 8-deep. ----
    #pragma unroll
    for (int p = 0; p < 2; ++p) {
        int unit = p * 512 + tid;
        if (unit < (VTILE / 8) * 16) {
            int kq8 = unit >> 4, hq = unit & 15;
            int g   = g0 + kq8 * 8;
            i32x4 wd[4];
            #pragma unroll
            for (int rr = 0; rr < 4; ++rr) {
                int ga = g + rr * 2, gb = ga + 1;
                f32x4 ya = gload(vg + (size_t)ga * ROWSTR + hq * 4, ga >= 0 && ga < S_LEN);
                f32x4 yb = gload(vg + (size_t)gb * ROWSTR + hq * 4, gb >= 0 && gb < S_LEN);
                #pragma unroll
                for (int i = 0; i < 4; ++i)
                    wd[i][rr] = (int)cvt_pk(ya[i], yb[i]);
            }
            #pragma unroll
            for (int i = 0; i < 4; ++i)
                *(i32x4*)((char*)Tile + voff(hq * 4 + i, kq8 * 8)) = wd[i];
        }
    }
    __syncthreads();   // V^T ready

    // ---- phase D: P -> A-frags (shuffles) + PV + 1/d + stores ----
    const int sA = ((u & 1) * 2) * 16 + c16;
    const int sB = sA + 16;
    const bool hiHalf = (u >> 1) != 0;

    s16x8 pa[5];
    #pragma unroll
    for (int kf = 0; kf < 5; ++kf) {
        const int jtA = 2 * kf;        // tile feeding dest u<2 (0..8)
        const int jtB = 2 * kf + 1;    // tile feeding dest u>=2 (9 -> zero)
        int a0, a1, b0, b1;
        int e0 = 0, e1 = 0, f0 = 0, f1 = 0;
        a0 = __shfl(w0[jtA], sA, 64); a1 = __shfl(w1[jtA], sA, 64);
        b0 = __shfl(w0[jtA], sB, 64); b1 = __shfl(w1[jtA], sB, 64);
        if (jtB <= 8) {
            e0 = __shfl(w0[jtB], sA, 64); e1 = __shfl(w1[jtB], sA, 64);
            f0 = __shfl(w0[jtB], sB, 64); f1 = __shfl(w1[jtB], sB, 64);
        }
        i32x4 wd;
        wd[0] = hiHalf ? e0 : a0;
        wd[1] = hiHalf ? e1 : a1;
        wd[2] = hiHalf ? f0 : b0;
        wd[3] = hiHalf ? f1 : b1;
        pa[kf] = __builtin_bit_cast(s16x8, wd);
    }

    // fetch 1/d for this lane's 4 output rows (queries u*4+r)
    float rq[4];
    #pragma unroll
    for (int r = 0; r < 4; ++r)
        rq[r] = __shfl(rdv, u * 4 + r, 64);

    __builtin_amdgcn_s_setprio(1);
    #pragma unroll
    for (int ht = 0; ht < 4; ++ht) {
        f32x4 o = {0.f, 0.f, 0.f, 0.f};
        #pragma unroll
        for (int kf = 0; kf < 5; ++kf) {
            s16x8 bv = *(const s16x8*)((const char*)Tile +
                         voff(ht * 16 + c16, w * 16 + kf * 32 + u * 8));   // col <= 264
            o = __builtin_amdgcn_mfma_f32_16x16x32_bf16(pa[kf], bv, o, 0, 0, 0);
        }
        #pragma unroll
        for (int r = 0; r < 4; ++r) {
            int p = qw + u * 4 + r;
            if (p < S_LEN)
                __builtin_nontemporal_store(o[r] * rq[r],
                    &out[bn + (size_t)p * ROWSTR + ht * 16 + c16]);
        }
    }
    __builtin_amdgcn_s_setprio(0);
}

extern "C" void kernel_launch(void* const* d_in, const int* in_sizes, int n_in,
                              void* d_out, int out_size, void* d_ws, size_t ws_size,
                              hipStream_t stream) {
    const float* q = (const float*)d_in[0];
    const float* k = (const float*)d_in[1];
    const float* v = (const float*)d_in[2];
    float* o = (float*)d_out;
    const int B = in_sizes[0] / (S_LEN * NHEAD * HDIM);
    dim3 grid(32 * NHEAD * B);   // 2048 blocks, XCD-swizzled in-kernel
    win_attn<<<grid, dim3(512), 0, stream>>>(q, k, v, o);
}

// Round 17
// 51.183 us; speedup vs baseline: 1.1031x; 1.0613x over previous
//
#include <hip/hip_runtime.h>

// Window attention, b=8 s=4094 nh=8 h=64, radius 63, f32 I/O.
// Round 17 (final) = r13 (best, 53.5us) + only the verified-neutral-or-
// positive pieces of r16: b128 K staging (8->4 DS writes, uniform banks)
// and s_setprio around MFMA clusters (T5). Dropped: nontemporal stores
// (raised WRITE 65->87 MB) and V^T b128 writes (raised conflicts 2->3.8M).
//
// 16-round lever map (all flat or small): occupancy 16->32w +5%; instr
// cuts 0%; barriers 3->1 0%; round-trips 2->1 0%; streams 4->6 -4%;
// DS compression 0%. Plateau ~53.5us, latency-bound, no pipe >30%.
//
// Structure: 512-thr blocks / 128 q; wave owns 16 q. Two-phase 34.9 KiB
// LDS tile: K [256][64] bf16 swizzled -> V^T [64][272] bf16 swizzled.
// No-max exp2 softmax (|s|<~6 -> exact), deferred 1/d, XCD swizzle,
// conflict-permuted V^T b64 writes, launch_bounds(512,4).
//
// MFMA 16x16x32 bf16 layouts (verified rounds 1-16):
//   A: lane l holds A[row=l&15][k=(l>>4)*8+j]   B: B[k=(l>>4)*8+j][col=l&15]
//   D: lane l reg r holds D[row=(l>>4)*4+r][col=l&15]

#define S_LEN 4094
#define NHEAD 8
#define HDIM  64
#define ROWSTR 512
#define KTILE 256            // staged K rows (keys)
#define VTILE 272            // staged V^T cols (keys)

typedef float f32x4 __attribute__((ext_vector_type(4)));
typedef short s16x8 __attribute__((ext_vector_type(8)));
typedef int   i32x2 __attribute__((ext_vector_type(2)));
typedef int   i32x4 __attribute__((ext_vector_type(4)));

#define QSCALE 0.1803368801f   // 0.125 * log2(e)

static __device__ __forceinline__ unsigned cvt_pk(float lo, float hi) {
    unsigned r;
    asm("v_cvt_pk_bf16_f32 %0, %1, %2" : "=v"(r) : "v"(lo), "v"(hi));
    return r;
}

// K view: [256 keys][64 h] bf16, row 128 B, swizzle ^((key&7)<<4)
static __device__ __forceinline__ int koff(int kr, int h) {
    return ((kr << 7) + (h << 1)) ^ ((kr & 7) << 4);
}
// V^T view: [64 h][272 keys] bf16, row 544 B, swizzle ^((h&7)<<4)
static __device__ __forceinline__ int voff(int h, int kc) {
    return (h * (VTILE * 2) + (kc << 1)) ^ ((h & 7) << 4);
}

static __device__ __forceinline__ f32x4 gload(const float* p, bool ok) {
    f32x4 x = {0.f, 0.f, 0.f, 0.f};
    if (ok) x = *(const f32x4*)p;
    return x;
}

static __device__ __forceinline__ s16x8 pack8(f32x4 x0, f32x4 x1) {
    i32x4 wd;
    wd[0] = (int)cvt_pk(x0[0], x0[1]); wd[1] = (int)cvt_pk(x0[2], x0[3]);
    wd[2] = (int)cvt_pk(x1[0], x1[1]); wd[3] = (int)cvt_pk(x1[2], x1[3]);
    return __builtin_bit_cast(s16x8, wd);
}

__global__ __launch_bounds__(512, 4)
void win_attn(const float* __restrict__ q, const float* __restrict__ k,
              const float* __restrict__ v, float* __restrict__ out)
{
    __shared__ __align__(16) short Tile[64 * VTILE + 64];   // 34.9 KiB, K then V^T

    const int tid  = threadIdx.x;
    const int lane = tid & 63;
    const int w    = tid >> 6;      // wave 0..7
    const int u    = lane >> 4;
    const int c16  = lane & 15;

    // ---- T1: XCD-bijective swizzle (2048 = 8 XCD x 256 contiguous) ----
    const int wg  = (int)blockIdx.x;
    const int swz = (wg & 7) * 256 + (wg >> 3);
    const int cx  = swz & 31;          // q-chunk 0..31
    const int rem = swz >> 5;
    const int hn  = rem & 7;           // head
    const int bz  = rem >> 3;          // batch

    const int q0 = cx * 128;
    const int g0 = q0 - 63;                      // key of tile index 0
    const int qw = q0 + w * 16;                  // this wave's first query
    const size_t bn = (size_t)bz * (S_LEN * ROWSTR) + (size_t)hn * HDIM;
    const float* qg = q + bn;
    const float* kg = k + bn;
    const float* vg = v + bn;

    // ---- Q loads issued first (hide under K staging) ----
    f32x4 qld[4];
    {
        int qr = qw + c16; if (qr > S_LEN - 1) qr = S_LEN - 1;
        const float* qp = qg + (size_t)qr * ROWSTR + u * 8;
        qld[0] = *(const f32x4*)(qp);
        qld[1] = *(const f32x4*)(qp + 4);
        qld[2] = *(const f32x4*)(qp + 32);
        qld[3] = *(const f32x4*)(qp + 36);
    }

    // ---- phase A: stage K. 256 rows x 8 h-octs = 2048 units, 4/thread.
    //      b128 writes, bank start 4*(ho^(kr&7)): uniform 8-deep. ----
    #pragma unroll
    for (int p = 0; p < 4; ++p) {
        int unit = p * 512 + tid;
        int kr = unit >> 3, ho = unit & 7;
        int g  = g0 + kr;
        bool ok = (g >= 0) && (g < S_LEN);
        const float* kp = kg + (size_t)g * ROWSTR + ho * 8;
        f32x4 x0 = gload(kp, ok);
        f32x4 x1 = gload(kp + 4, ok);
        i32x4 wd;
        wd[0] = (int)cvt_pk(x0[0], x0[1]); wd[1] = (int)cvt_pk(x0[2], x0[3]);
        wd[2] = (int)cvt_pk(x1[0], x1[1]); wd[3] = (int)cvt_pk(x1[2], x1[3]);
        *(i32x4*)((char*)Tile + koff(kr, ho * 8)) = wd;
    }
    __syncthreads();   // K tile ready

    // ---- phase B: QK^T (9 tiles) + no-max exp2 softmax; P packed to regs ----
    s16x8 bq[2];
    #pragma unroll
    for (int hf = 0; hf < 2; ++hf) {
        f32x4 x0 = qld[hf * 2]     * QSCALE;
        f32x4 x1 = qld[hf * 2 + 1] * QSCALE;
        bq[hf] = pack8(x0, x1);
    }

    f32x4 sc[9];
    __builtin_amdgcn_s_setprio(1);
    #pragma unroll
    for (int j = 0; j < 9; ++j) {
        int krow = w * 16 + j * 16 + c16;   // <= 255
        s16x8 ka0 = *(const s16x8*)((const char*)Tile + koff(krow, u * 8));
        s16x8 ka1 = *(const s16x8*)((const char*)Tile + koff(krow, 32 + u * 8));
        f32x4 acc = {0.f, 0.f, 0.f, 0.f};
        acc = __builtin_amdgcn_mfma_f32_16x16x32_bf16(ka0, bq[0], acc, 0, 0, 0);
        acc = __builtin_amdgcn_mfma_f32_16x16x32_bf16(ka1, bq[1], acc, 0, 0, 0);
        sc[j] = acc;
    }
    __builtin_amdgcn_s_setprio(0);

    // band mask (only tiles 0,7,8 can violate); exp2; P pack; 1/d deferred
    const int iq = c16;
    float d = 0.f;
    int w0[9], w1[9];
    #pragma unroll
    for (int j = 0; j < 9; ++j) {
        #pragma unroll
        for (int r = 0; r < 4; ++r) {
            float s = sc[j][r];
            if (j == 0 || j >= 7) {
                int tl = j * 16 + u * 4 + r;
                bool inb = (tl >= iq) && (tl <= iq + 126);
                s = inb ? s : -__builtin_inff();
            }
            float pv = __builtin_amdgcn_exp2f(s);   // 2^s; 2^-inf = 0
            sc[j][r] = pv;
            d += pv;
        }
    }
    #pragma unroll
    for (int j = 0; j < 9; ++j) {
        w0[j] = (int)cvt_pk(sc[j][0], sc[j][1]);
        w1[j] = (int)cvt_pk(sc[j][2], sc[j][3]);
    }
    d += __shfl_xor(d, 16, 64);
    d += __shfl_xor(d, 32, 64);
    const float rdv = 1.f / d;
    __syncthreads();   // all waves done reading K tile

    // ---- phase C: stage V^T (68 key-quads x 16 h-quads = 1088 units),
    //      b64 writes with i-permutation (r13's verified pattern) ----
    #pragma unroll
    for (int p = 0; p < 3; ++p) {
        int unit = p * 512 + tid;
        if (unit < (VTILE / 4) * 16) {
            int kq = unit >> 4, hq = unit & 15;
            int g  = g0 + kq * 4;
            f32x4 y0 = gload(vg + (size_t)(g + 0) * ROWSTR + hq * 4, g + 0 >= 0 && g + 0 < S_LEN);
            f32x4 y1 = gload(vg + (size_t)(g + 1) * ROWSTR + hq * 4, g + 1 >= 0 && g + 1 < S_LEN);
            f32x4 y2 = gload(vg + (size_t)(g + 2) * ROWSTR + hq * 4, g + 2 >= 0 && g + 2 < S_LEN);
            f32x4 y3 = gload(vg + (size_t)(g + 3) * ROWSTR + hq * 4, g + 3 >= 0 && g + 3 < S_LEN);
            #pragma unroll
            for (int ii = 0; ii < 4; ++ii) {
                int i = (ii + (hq >> 1)) & 3;        // spread h&7 across lanes
                int h = hq * 4 + i;
                i32x2 wd;
                wd[0] = (int)cvt_pk(y0[i], y1[i]);
                wd[1] = (int)cvt_pk(y2[i], y3[i]);
                *(i32x2*)((char*)Tile + voff(h, kq * 4)) = wd;
            }
        }
    }
    __syncthreads();   // V^T ready

    // ---- phase D: P -> A-frags (shuffles) + PV + 1/d + stores ----
    const int sA = ((u & 1) * 2) * 16 + c16;
    const int sB = sA + 16;
    const bool hiHalf = (u >> 1) != 0;

    s16x8 pa[5];
    #pragma unroll
    for (int kf = 0; kf < 5; ++kf) {
        const int jtA = 2 * kf;        // tile feeding dest u<2 (0..8)
        const int jtB = 2 * kf + 1;    // tile feeding dest u>=2 (9 -> zero)
        int a0, a1, b0, b1;
        int e0 = 0, e1 = 0, f0 = 0, f1 = 0;
        a0 = __shfl(w0[jtA], sA, 64); a1 = __shfl(w1[jtA], sA, 64);
        b0 = __shfl(w0[jtA], sB, 64); b1 = __shfl(w1[jtA], sB, 64);
        if (jtB <= 8) {
            e0 = __shfl(w0[jtB], sA, 64); e1 = __shfl(w1[jtB], sA, 64);
            f0 = __shfl(w0[jtB], sB, 64); f1 = __shfl(w1[jtB], sB, 64);
        }
        i32x4 wd;
        wd[0] = hiHalf ? e0 : a0;
        wd[1] = hiHalf ? e1 : a1;
        wd[2] = hiHalf ? f0 : b0;
        wd[3] = hiHalf ? f1 : b1;
        pa[kf] = __builtin_bit_cast(s16x8, wd);
    }

    // fetch 1/d for this lane's 4 output rows (queries u*4+r)
    float rq[4];
    #pragma unroll
    for (int r = 0; r < 4; ++r)
        rq[r] = __shfl(rdv, u * 4 + r, 64);

    __builtin_amdgcn_s_setprio(1);
    #pragma unroll
    for (int ht = 0; ht < 4; ++ht) {
        f32x4 o = {0.f, 0.f, 0.f, 0.f};
        #pragma unroll
        for (int kf = 0; kf < 5; ++kf) {
            s16x8 bv = *(const s16x8*)((const char*)Tile +
                         voff(ht * 16 + c16, w * 16 + kf * 32 + u * 8));   // col <= 264
            o = __builtin_amdgcn_mfma_f32_16x16x32_bf16(pa[kf], bv, o, 0, 0, 0);
        }
        #pragma unroll
        for (int r = 0; r < 4; ++r) {
            int p = qw + u * 4 + r;
            if (p < S_LEN)
                out[bn + (size_t)p * ROWSTR + ht * 16 + c16] = o[r] * rq[r];
        }
    }
    __builtin_amdgcn_s_setprio(0);
}

extern "C" void kernel_launch(void* const* d_in, const int* in_sizes, int n_in,
                              void* d_out, int out_size, void* d_ws, size_t ws_size,
                              hipStream_t stream) {
    const float* q = (const float*)d_in[0];
    const float* k = (const float*)d_in[1];
    const float* v = (const float*)d_in[2];
    float* o = (float*)d_out;
    const int B = in_sizes[0] / (S_LEN * NHEAD * HDIM);
    dim3 grid(32 * NHEAD * B);   // 2048 blocks, XCD-swizzled in-kernel
    win_attn<<<grid, dim3(512), 0, stream>>>(q, k, v, o);
}